// Round 1
// baseline (239.205 us; speedup 1.0000x reference)
//
#include <hip/hip_runtime.h>
#include <hip/hip_bf16.h>

using bf16x8 = __attribute__((ext_vector_type(8))) __bf16;
using f32x4  = __attribute__((ext_vector_type(4))) float;

#define M_DIM 16384
#define K_DIM 4096
#define N_DIM 1024

__device__ __forceinline__ unsigned short f2bf(float f) {
  __hip_bfloat16 h = __float2bfloat16(f);  // RNE
  return *reinterpret_cast<unsigned short*>(&h);
}

// nearest-grid magnitude for |xs|; thresholds are the positive midpoints.
// strict '>' matches searchsorted side='left' tie-down semantics for xs>0.
__device__ __forceinline__ float snap(float a) {
  float q = 0.0f;
  q += (a > 0.25f) ? 0.5f : 0.0f;
  q += (a > 0.75f) ? 0.5f : 0.0f;
  q += (a > 1.25f) ? 0.5f : 0.0f;
  q += (a > 1.75f) ? 0.5f : 0.0f;
  q += (a > 2.5f)  ? 1.0f : 0.0f;
  q += (a > 3.5f)  ? 1.0f : 0.0f;
  q += (a > 5.0f)  ? 2.0f : 0.0f;
  return q;
}

__device__ __forceinline__ unsigned short qdq(float xv, float rs, float scale) {
  float xs = xv * rs;
  float q  = copysignf(snap(fabsf(xs)), xs);
  return f2bf(q * scale);
}

// One 16-lane cluster per 128-elem group; 4 groups per wave, 16 per block.
__global__ __launch_bounds__(256) void quant_kernel(const float* __restrict__ x,
                                                    unsigned short* __restrict__ dq) {
  const int wid = (blockIdx.x << 2) + (threadIdx.x >> 6);   // global wave id
  const int l   = threadIdx.x & 63;
  const int sub = l >> 4, t = l & 15;
  const size_t base = ((size_t)wid * 4 + sub) * 128;
  const float4* px = reinterpret_cast<const float4*>(x + base);
  float4 v0 = px[t];
  float4 v1 = px[16 + t];
  float amax = fmaxf(fmaxf(fmaxf(fabsf(v0.x), fabsf(v0.y)), fmaxf(fabsf(v0.z), fabsf(v0.w))),
                     fmaxf(fmaxf(fabsf(v1.x), fabsf(v1.y)), fmaxf(fabsf(v1.z), fabsf(v1.w))));
  #pragma unroll
  for (int m = 1; m < 16; m <<= 1) amax = fmaxf(amax, __shfl_xor(amax, m, 64));
  float scale = amax / 6.0f;                 // gmax = max|grid| = 6
  if (scale == 0.0f) scale = 1.0f;
  const float rs = 1.0f / scale;
  ushort4 o0, o1;
  o0.x = qdq(v0.x, rs, scale); o0.y = qdq(v0.y, rs, scale);
  o0.z = qdq(v0.z, rs, scale); o0.w = qdq(v0.w, rs, scale);
  o1.x = qdq(v1.x, rs, scale); o1.y = qdq(v1.y, rs, scale);
  o1.z = qdq(v1.z, rs, scale); o1.w = qdq(v1.w, rs, scale);
  reinterpret_cast<ushort4*>(dq + base)[t]      = o0;
  reinterpret_cast<ushort4*>(dq + base)[16 + t] = o1;
}

__global__ __launch_bounds__(256) void wconv_kernel(const float* __restrict__ w,
                                                    unsigned short* __restrict__ o) {
  const int n4 = (N_DIM * K_DIM) / 4;
  for (int i = blockIdx.x * 256 + threadIdx.x; i < n4; i += gridDim.x * 256) {
    float4 v = reinterpret_cast<const float4*>(w)[i];
    ushort4 u;
    u.x = f2bf(v.x); u.y = f2bf(v.y); u.z = f2bf(v.z); u.w = f2bf(v.w);
    reinterpret_cast<ushort4*>(o)[i] = u;
  }
}

// m97-structure GEMM: 128x128 tile, BK=64, 4 waves (2x2 of 64x64),
// 16x16x32 bf16 MFMA, global_load_lds width-16 staging, B^T input.
__global__ __launch_bounds__(256, 2) void gemm_kernel(const unsigned short* __restrict__ A,
                                                      const unsigned short* __restrict__ B,
                                                      const float* __restrict__ bias,
                                                      float* __restrict__ C) {
  __shared__ unsigned short lA[128 * 64];
  __shared__ unsigned short lB[128 * 64];
  const int bn = blockIdx.x, bm = blockIdx.y;
  const int tid = threadIdx.x;
  const int w = tid >> 6, l = tid & 63;
  const int wr = w >> 1, wc = w & 1;
  const int r = l & 15, h = l >> 4;

  f32x4 zero = {0.f, 0.f, 0.f, 0.f};
  f32x4 acc[4][4];
  #pragma unroll
  for (int m = 0; m < 4; ++m)
    #pragma unroll
    for (int n = 0; n < 4; ++n) acc[m][n] = zero;

  const int lrow = l >> 3;         // 0..7: row within 8-row staging chunk
  const int lcol = (l & 7) * 8;    // 0..56: bf16 elem offset within row
  const size_t a_base = (size_t)(bm * 128) * K_DIM;
  const size_t b_base = (size_t)(bn * 128) * K_DIM;

  for (int kt = 0; kt < K_DIM / 64; ++kt) {
    const int k0 = kt * 64;
    #pragma unroll
    for (int i = 0; i < 4; ++i) {
      const int c = (w << 2) + i;  // chunk: 8 rows x 64 cols = 1KB, wave-uniform
      const unsigned short* ga = A + a_base + (size_t)(c * 8 + lrow) * K_DIM + k0 + lcol;
      __builtin_amdgcn_global_load_lds((__attribute__((address_space(1))) void*)ga,
                                       (__attribute__((address_space(3))) void*)(&lA[c * 512]),
                                       16, 0, 0);
      const unsigned short* gb = B + b_base + (size_t)(c * 8 + lrow) * K_DIM + k0 + lcol;
      __builtin_amdgcn_global_load_lds((__attribute__((address_space(1))) void*)gb,
                                       (__attribute__((address_space(3))) void*)(&lB[c * 512]),
                                       16, 0, 0);
    }
    __syncthreads();
    #pragma unroll
    for (int ks = 0; ks < 2; ++ks) {
      bf16x8 aF[4], bF[4];
      #pragma unroll
      for (int m = 0; m < 4; ++m)
        aF[m] = *reinterpret_cast<const bf16x8*>(&lA[(wr * 64 + m * 16 + r) * 64 + ks * 32 + h * 8]);
      #pragma unroll
      for (int n = 0; n < 4; ++n)
        bF[n] = *reinterpret_cast<const bf16x8*>(&lB[(wc * 64 + n * 16 + r) * 64 + ks * 32 + h * 8]);
      #pragma unroll
      for (int m = 0; m < 4; ++m)
        #pragma unroll
        for (int n = 0; n < 4; ++n)
          acc[m][n] = __builtin_amdgcn_mfma_f32_16x16x32_bf16(aF[m], bF[n], acc[m][n], 0, 0, 0);
    }
    __syncthreads();
  }

  // epilogue: C/D layout col=lane&15, row=(lane>>4)*4+reg  [m89/m91]
  const int orow = bm * 128 + wr * 64;
  const int ocol = bn * 128 + wc * 64;
  #pragma unroll
  for (int n = 0; n < 4; ++n) {
    const int col = ocol + n * 16 + r;
    const float bv = bias[col];
    #pragma unroll
    for (int m = 0; m < 4; ++m) {
      const int rb = orow + m * 16 + h * 4;
      #pragma unroll
      for (int j = 0; j < 4; ++j)
        C[(size_t)(rb + j) * N_DIM + col] = acc[m][n][j] + bv;
    }
  }
}

// Emergency fallback if ws is too small: fused fp32, slow but correct.
__global__ __launch_bounds__(256) void fused_naive(const float* __restrict__ x,
                                                   const float* __restrict__ w,
                                                   const float* __restrict__ bias,
                                                   float* __restrict__ out) {
  __shared__ float xq[K_DIM];
  const int row = blockIdx.x;
  const float* xr = x + (size_t)row * K_DIM;
  const int t = threadIdx.x;
  const int g = t >> 3, s = t & 7;          // 32 groups x 8 threads
  float vals[16];
  float amax = 0.f;
  #pragma unroll
  for (int i = 0; i < 16; ++i) {
    vals[i] = xr[g * 128 + s * 16 + i];
    amax = fmaxf(amax, fabsf(vals[i]));
  }
  #pragma unroll
  for (int m = 1; m < 8; m <<= 1) amax = fmaxf(amax, __shfl_xor(amax, m, 64));
  float scale = amax / 6.0f;
  if (scale == 0.f) scale = 1.f;
  const float rs = 1.0f / scale;
  #pragma unroll
  for (int i = 0; i < 16; ++i) {
    float xs = vals[i] * rs;
    xq[g * 128 + s * 16 + i] = copysignf(snap(fabsf(xs)), xs) * scale;
  }
  __syncthreads();
  #pragma unroll
  for (int i = 0; i < 4; ++i) {
    const int o = i * 256 + t;
    const float* wrow = w + (size_t)o * K_DIM;
    float acc = 0.f;
    for (int k = 0; k < K_DIM; k += 4) {
      float4 wv = *reinterpret_cast<const float4*>(wrow + k);
      acc += xq[k] * wv.x + xq[k + 1] * wv.y + xq[k + 2] * wv.z + xq[k + 3] * wv.w;
    }
    out[(size_t)row * N_DIM + o] = acc + bias[o];
  }
}

extern "C" void kernel_launch(void* const* d_in, const int* in_sizes, int n_in,
                              void* d_out, int out_size, void* d_ws, size_t ws_size,
                              hipStream_t stream) {
  const float* x    = (const float*)d_in[0];
  const float* wgt  = (const float*)d_in[1];
  const float* bias = (const float*)d_in[2];
  // d_in[3] is the grid; it is the fixed ANT flint grid, hardcoded above.
  float* out = (float*)d_out;

  const size_t deq_bytes = (size_t)M_DIM * K_DIM * 2;   // 128 MiB bf16
  const size_t wb_bytes  = (size_t)N_DIM * K_DIM * 2;   // 8 MiB bf16
  if (ws_size >= deq_bytes + wb_bytes) {
    unsigned short* deq = (unsigned short*)d_ws;
    unsigned short* wb  = (unsigned short*)((char*)d_ws + deq_bytes);
    // groups total = M*K/128 = 524288; 16 groups/block -> 32768 blocks
    quant_kernel<<<(M_DIM * (K_DIM / 128)) / 16, 256, 0, stream>>>(x, deq);
    wconv_kernel<<<1024, 256, 0, stream>>>(wgt, wb);
    gemm_kernel<<<dim3(N_DIM / 128, M_DIM / 128), 256, 0, stream>>>(deq, wb, bias, out);
  } else {
    fused_naive<<<M_DIM, 256, 0, stream>>>(x, wgt, bias, out);
  }
}